// Round 1
// baseline (1283.914 us; speedup 1.0000x reference)
//
#include <hip/hip_runtime.h>

#define B_ 8
#define H_ 128
#define W_ 128
#define C_ 128

// mish(x) = x * tanh(softplus(x)) = x * (t^2 + 2t) / (t^2 + 2t + 2), t = e^x
__device__ __forceinline__ float mish_f(float x) {
    float t = __expf(fminf(x, 20.0f));   // x>20: ratio rounds to 1.0 -> mish=x
    float u = t * (t + 2.0f);
    return x * u / (u + 2.0f);
}

// XCD-locality swizzle: blocks with blk%8==k handle contiguous rows [k*128,(k+1)*128)
__device__ __forceinline__ int swz_row(int blk) {
    return ((blk & 7) << 7) | (blk >> 3);
}

// ---------------------------------------------------------------------------
// 1) bilinear backward warp: nxtw[b,y,x,c]
// grid 65536 x 256 (2 pixels per block, 128 channels each)
// ---------------------------------------------------------------------------
__global__ __launch_bounds__(256) void warp_kernel(
    const float* __restrict__ nxt, const float* __restrict__ flo,
    float* __restrict__ nxtw)
{
    const int tid = threadIdx.x;
    const int c   = tid & 127;
    const int pix = blockIdx.x * 2 + (tid >> 7);
    const int b   = pix >> 14;
    const int rem = pix & 16383;
    const int y   = rem >> 7;
    const int x   = rem & 127;

    const float fx = flo[(size_t)pix * 2 + 0];
    const float fy = flo[(size_t)pix * 2 + 1];
    const float xf = (float)x + fx;
    const float yf = (float)y + fy;
    const int x0 = (int)xf;            // trunc toward zero == astype(int32)
    const int y0 = (int)yf;
    const int x0c = min(max(x0, 0), W_ - 1);
    const int x1c = min(max(x0 + 1, 0), W_ - 1);
    const int y0c = min(max(y0, 0), H_ - 1);
    const int y1c = min(max(y0 + 1, 0), H_ - 1);
    const float x0f = (float)x0c, x1f = (float)x1c;
    const float y0f = (float)y0c, y1f = (float)y1c;
    const float wa = (x1f - xf) * (y1f - yf);
    const float wb = (x1f - xf) * (yf - y0f);
    const float wc = (xf - x0f) * (y1f - yf);
    const float wd = (xf - x0f) * (yf - y0f);

    const float* base = nxt + (size_t)b * H_ * W_ * C_;
    const float Ia = base[((size_t)y0c * W_ + x0c) * C_ + c];
    const float Ib = base[((size_t)y1c * W_ + x0c) * C_ + c];
    const float Ic = base[((size_t)y0c * W_ + x1c) * C_ + c];
    const float Id = base[((size_t)y1c * W_ + x1c) * C_ + c];
    nxtw[(size_t)pix * C_ + c] = wa * Ia + wb * Ib + wc * Ic + wd * Id;
}

// ---------------------------------------------------------------------------
// 2) cost volume: cost[b,y,x,(dy+4)*9+(dx+4)] = mean_c prv[p,c]*nxtw[p+d,c]
// one block per (b,y) row; 256 thr = 32 x-groups(4px) x 8 channel-splits
// ---------------------------------------------------------------------------
__global__ __launch_bounds__(256) void costvol_kernel(
    const float* __restrict__ prv, const float* __restrict__ nxtw,
    float* __restrict__ cost)
{
    constexpr int NSTR = 140;                 // 136 + pad, mult of 4 for b128
    __shared__ float NL[32 * NSTR];
    const int tid = threadIdx.x;
    const int cs  = tid & 7;
    const int xg  = tid >> 3;
    const int x0  = xg * 4;
    const int r   = swz_row(blockIdx.x);      // b*H + y
    const int y   = r & 127;
    const int b   = r >> 7;
    const float* prow = prv + (size_t)r * (W_ * C_);

    for (int dy = -4; dy <= 4; ++dy) {
        const int q = y + dy;                 // block-uniform
        if (q >= 0 && q < H_) {
            float acc[4][9];
            #pragma unroll
            for (int i = 0; i < 4; ++i)
                #pragma unroll
                for (int d = 0; d < 9; ++d) acc[i][d] = 0.0f;

            const float* nrow = nxtw + ((size_t)b * H_ + q) * (W_ * C_);
            for (int cc = 0; cc < 4; ++cc) {  // channel chunks of 32
                __syncthreads();
                for (int idx = tid; idx < 32 * 136; idx += 256) {
                    const int cl = idx & 31;
                    const int xh = idx >> 5;
                    const int xx = xh - 4;
                    float v = 0.0f;
                    if (xx >= 0 && xx < W_) v = nrow[(size_t)xx * C_ + cc * 32 + cl];
                    NL[cl * NSTR + xh] = v;
                }
                __syncthreads();

                float pv[4][4];
                #pragma unroll
                for (int i = 0; i < 4; ++i) {
                    float4 t = *(const float4*)&prow[(size_t)(x0 + i) * C_ + cc * 32 + cs * 4];
                    pv[0][i] = t.x; pv[1][i] = t.y; pv[2][i] = t.z; pv[3][i] = t.w;
                }
                #pragma unroll
                for (int k = 0; k < 4; ++k) {
                    const int cl = cs * 4 + k;
                    const float* nl = &NL[cl * NSTR + x0];
                    float n[12];
                    float4 n0 = *(const float4*)(nl);
                    float4 n1 = *(const float4*)(nl + 4);
                    float4 n2 = *(const float4*)(nl + 8);
                    n[0]=n0.x; n[1]=n0.y; n[2]=n0.z;  n[3]=n0.w;
                    n[4]=n1.x; n[5]=n1.y; n[6]=n1.z;  n[7]=n1.w;
                    n[8]=n2.x; n[9]=n2.y; n[10]=n2.z; n[11]=n2.w;
                    #pragma unroll
                    for (int i = 0; i < 4; ++i)
                        #pragma unroll
                        for (int d = 0; d < 9; ++d)
                            acc[i][d] += pv[k][i] * n[i + d];
                }
            }
            // reduce over the 8 channel-splits (lanes differ in bits 0..2)
            #pragma unroll
            for (int i = 0; i < 4; ++i)
                #pragma unroll
                for (int d = 0; d < 9; ++d) {
                    float v = acc[i][d];
                    v += __shfl_xor(v, 1);
                    v += __shfl_xor(v, 2);
                    v += __shfl_xor(v, 4);
                    acc[i][d] = v * (1.0f / 128.0f);
                }
            if (cs == 0) {
                #pragma unroll
                for (int i = 0; i < 4; ++i) {
                    const size_t base = ((size_t)r * W_ + (x0 + i)) * 81 + (size_t)(dy + 4) * 9;
                    #pragma unroll
                    for (int d = 0; d < 9; ++d) cost[base + d] = acc[i][d];
                }
            }
        } else {
            if (cs == 0) {
                #pragma unroll
                for (int i = 0; i < 4; ++i) {
                    const size_t base = ((size_t)r * W_ + (x0 + i)) * 81 + (size_t)(dy + 4) * 9;
                    #pragma unroll
                    for (int d = 0; d < 9; ++d) cost[base + d] = 0.0f;
                }
            }
        }
    }
}

// ---------------------------------------------------------------------------
// 3) fused depthwise3x3 + pointwise + bias + mish, one block per (b,h) row.
// Layer0 reads the virtual concat [cost(81) | prv(128) | flo(2)].
// Thread tile PXT px x OPT outs; out index o = og + OGN*j (conflict-free LDS).
// ---------------------------------------------------------------------------
template<int CIN, bool IS_L0>
__device__ __forceinline__ float read_x(const float* __restrict__ in,
    const float* __restrict__ cost, const float* __restrict__ prv,
    const float* __restrict__ flo, int b, int y, int x, int c)
{
    const size_t p = ((size_t)b * H_ + y) * W_ + x;
    if constexpr (IS_L0) {
        if (c < 81)  return cost[p * 81 + c];
        if (c < 209) return prv[p * 128 + (c - 81)];
        return flo[p * 2 + (c - 209)];
    } else {
        return in[p * CIN + c];
    }
}

template<int CIN, int COUT, int OPT, int PXT, bool ACT, bool IS_L0>
__global__ __launch_bounds__(256, 2) void sepconv_kernel(
    const float* __restrict__ in,
    const float* __restrict__ cost, const float* __restrict__ prv,
    const float* __restrict__ flo,
    const float* __restrict__ dw, const float* __restrict__ pw,
    const float* __restrict__ bias, float* __restrict__ out)
{
    constexpr int OGN  = COUT / OPT;          // 16 (L0-4) or 2 (L5) — pow2
    constexpr int DSTR = 132;                 // 128 + pad (mult of 4)
    static_assert(OGN * (W_ / PXT) == 256, "thread tiling must cover 256 threads");
    __shared__ float dwres[32 * DSTR];        // depthwise result, chunk of 32 ch
    __shared__ float pwl[32 * COUT];          // pw chunk [k][o]
    __shared__ float dwl[9 * CIN];            // depthwise weights [tap][c]

    const int tid = threadIdx.x;
    const int r   = swz_row(blockIdx.x);      // b*H + h
    const int h   = r & 127;
    const int b   = r >> 7;

    for (int i = tid; i < 9 * CIN; i += 256) dwl[i] = dw[i];

    const int og  = tid & (OGN - 1);
    const int pg  = tid / OGN;
    const int px0 = pg * PXT;

    float acc[PXT][OPT];
    #pragma unroll
    for (int i = 0; i < PXT; ++i)
        #pragma unroll
        for (int j = 0; j < OPT; ++j) acc[i][j] = 0.0f;

    for (int c0 = 0; c0 < CIN; c0 += 32) {
        const int kc = (CIN - c0 < 32) ? (CIN - c0) : 32;
        __syncthreads();                       // protect LDS reuse
        // stage pw chunk
        for (int idx = tid; idx < kc * COUT; idx += 256) {
            const int k = idx / COUT;
            const int o = idx - k * COUT;
            pwl[k * COUT + o] = pw[(size_t)(c0 + k) * COUT + o];
        }
        // depthwise for this channel chunk: entries (c in [0,32), pxg in [0,32))
        for (int e = tid; e < 32 * 32; e += 256) {
            const int c   = e & 31;
            const int pxg = e >> 5;
            if (c < kc) {
                const int cg = c0 + c;
                const int xb = pxg * 4;
                float wreg[9];
                #pragma unroll
                for (int t = 0; t < 9; ++t) wreg[t] = dwl[t * CIN + cg];
                float val[3][6];
                #pragma unroll
                for (int ky = 0; ky < 3; ++ky) {
                    const int yy = h + ky - 1;
                    const bool yok = (yy >= 0) & (yy < H_);
                    #pragma unroll
                    for (int m = 0; m < 6; ++m) {
                        const int xx = xb - 1 + m;
                        const bool ok = yok & (xx >= 0) & (xx < W_);
                        val[ky][m] = ok ? read_x<CIN, IS_L0>(in, cost, prv, flo, b, yy, xx, cg) : 0.0f;
                    }
                }
                float a[4];
                #pragma unroll
                for (int i = 0; i < 4; ++i) {
                    float s = 0.0f;
                    #pragma unroll
                    for (int ky = 0; ky < 3; ++ky)
                        #pragma unroll
                        for (int kx = 0; kx < 3; ++kx)
                            s += wreg[ky * 3 + kx] * val[ky][i + kx];
                    a[i] = s;
                }
                *(float4*)&dwres[c * DSTR + xb] = make_float4(a[0], a[1], a[2], a[3]);
            }
        }
        __syncthreads();
        // GEMM accumulate over this chunk
        #pragma unroll 4
        for (int k = 0; k < kc; ++k) {
            float av[PXT];
            if constexpr (PXT == 8) {
                float4 a0 = *(const float4*)&dwres[k * DSTR + px0];
                float4 a1 = *(const float4*)&dwres[k * DSTR + px0 + 4];
                av[0]=a0.x; av[1]=a0.y; av[2]=a0.z; av[3]=a0.w;
                av[4]=a1.x; av[5]=a1.y; av[6]=a1.z; av[7]=a1.w;
            } else {
                av[0] = dwres[k * DSTR + px0];
            }
            #pragma unroll
            for (int j = 0; j < OPT; ++j) {
                const float wv = pwl[k * COUT + og + OGN * j];
                #pragma unroll
                for (int i = 0; i < PXT; ++i)
                    acc[i][j] += av[i] * wv;
            }
        }
    }
    // epilogue: bias + mish + store
    float bj[OPT];
    #pragma unroll
    for (int j = 0; j < OPT; ++j) bj[j] = (bias != nullptr) ? bias[og + OGN * j] : 0.0f;
    #pragma unroll
    for (int i = 0; i < PXT; ++i) {
        const size_t obase = ((size_t)r * W_ + px0 + i) * COUT + og;
        #pragma unroll
        for (int j = 0; j < OPT; ++j) {
            const float x = acc[i][j] + bj[j];
            out[obase + (size_t)OGN * j] = ACT ? mish_f(x) : x;
        }
    }
}

// ---------------------------------------------------------------------------
extern "C" void kernel_launch(void* const* d_in, const int* in_sizes, int n_in,
                              void* d_out, int out_size, void* d_ws, size_t ws_size,
                              hipStream_t stream)
{
    (void)in_sizes; (void)n_in; (void)out_size; (void)ws_size;
    const float* prv = (const float*)d_in[0];
    const float* nxt = (const float*)d_in[1];
    const float* flo = (const float*)d_in[2];
    const float* dw0 = (const float*)d_in[3];
    const float* pw0 = (const float*)d_in[4];
    const float* b0  = (const float*)d_in[5];
    const float* dw1 = (const float*)d_in[6];
    const float* pw1 = (const float*)d_in[7];
    const float* b1  = (const float*)d_in[8];
    const float* dw2 = (const float*)d_in[9];
    const float* pw2 = (const float*)d_in[10];
    const float* b2  = (const float*)d_in[11];
    const float* dw3 = (const float*)d_in[12];
    const float* pw3 = (const float*)d_in[13];
    const float* b3  = (const float*)d_in[14];
    const float* dw4 = (const float*)d_in[15];
    const float* pw4 = (const float*)d_in[16];
    const float* b4  = (const float*)d_in[17];
    const float* dw5 = (const float*)d_in[18];
    const float* pw5 = (const float*)d_in[19];

    // ws layout: bufA [0, 64MiB) ; bufC [64MiB, 128MiB)  (cost aliases bufC)
    float* bufA  = (float*)d_ws;
    float* bufC  = (float*)((char*)d_ws + (size_t)67108864);
    float* costb = bufC;
    float* outp  = (float*)d_out;
    const float* nullf = nullptr;

    warp_kernel<<<65536, 256, 0, stream>>>(nxt, flo, bufA);
    costvol_kernel<<<1024, 256, 0, stream>>>(prv, bufA, costb);
    // L0: 211 -> 128 (reads cost/prv/flo virtually, nxtw in bufA is dead)
    sepconv_kernel<211, 128, 8, 8, true,  true ><<<1024, 256, 0, stream>>>(
        nullf, costb, prv, flo, dw0, pw0, b0, bufA);
    // L1: 128 -> 128
    sepconv_kernel<128, 128, 8, 8, true,  false><<<1024, 256, 0, stream>>>(
        bufA, nullf, nullf, nullf, dw1, pw1, b1, bufC);
    // L2: 128 -> 96
    sepconv_kernel<128,  96, 6, 8, true,  false><<<1024, 256, 0, stream>>>(
        bufC, nullf, nullf, nullf, dw2, pw2, b2, bufA);
    // L3: 96 -> 64
    sepconv_kernel< 96,  64, 4, 8, true,  false><<<1024, 256, 0, stream>>>(
        bufA, nullf, nullf, nullf, dw3, pw3, b3, bufC);
    // L4: 64 -> 32
    sepconv_kernel< 64,  32, 2, 8, true,  false><<<1024, 256, 0, stream>>>(
        bufC, nullf, nullf, nullf, dw4, pw4, b4, bufA);
    // L5: 32 -> 2, no bias, no activation
    sepconv_kernel< 32,   2, 1, 1, false, false><<<1024, 256, 0, stream>>>(
        bufA, nullf, nullf, nullf, dw5, pw5, nullf, outp);
}

// Round 2
// 775.873 us; speedup vs baseline: 1.6548x; 1.6548x over previous
//
#include <hip/hip_runtime.h>

#define B_ 8
#define H_ 128
#define W_ 128
#define C_ 128

// mish(x) = x * tanh(softplus(x)) = x * (t^2 + 2t) / (t^2 + 2t + 2), t = e^x
__device__ __forceinline__ float mish_f(float x) {
    float t = __expf(fminf(x, 20.0f));   // x>20: ratio rounds to 1.0 -> mish=x
    float u = t * (t + 2.0f);
    return x * u / (u + 2.0f);
}

// XCD-locality swizzle: blocks with blk%8==k handle contiguous rows [k*128,(k+1)*128)
__device__ __forceinline__ int swz_row(int blk) {
    return ((blk & 7) << 7) | (blk >> 3);
}

// ---------------------------------------------------------------------------
// 1) bilinear backward warp: nxtw[b,y,x,c]
// ---------------------------------------------------------------------------
__global__ __launch_bounds__(256) void warp_kernel(
    const float* __restrict__ nxt, const float* __restrict__ flo,
    float* __restrict__ nxtw)
{
    const int tid = threadIdx.x;
    const int c   = tid & 127;
    const int pix = blockIdx.x * 2 + (tid >> 7);
    const int b   = pix >> 14;
    const int rem = pix & 16383;
    const int y   = rem >> 7;
    const int x   = rem & 127;

    const float fx = flo[(size_t)pix * 2 + 0];
    const float fy = flo[(size_t)pix * 2 + 1];
    const float xf = (float)x + fx;
    const float yf = (float)y + fy;
    const int x0 = (int)xf;            // trunc toward zero == astype(int32)
    const int y0 = (int)yf;
    const int x0c = min(max(x0, 0), W_ - 1);
    const int x1c = min(max(x0 + 1, 0), W_ - 1);
    const int y0c = min(max(y0, 0), H_ - 1);
    const int y1c = min(max(y0 + 1, 0), H_ - 1);
    const float x0f = (float)x0c, x1f = (float)x1c;
    const float y0f = (float)y0c, y1f = (float)y1c;
    const float wa = (x1f - xf) * (y1f - yf);
    const float wb = (x1f - xf) * (yf - y0f);
    const float wc = (xf - x0f) * (y1f - yf);
    const float wd = (xf - x0f) * (yf - y0f);

    const float* base = nxt + (size_t)b * H_ * W_ * C_;
    const float Ia = base[((size_t)y0c * W_ + x0c) * C_ + c];
    const float Ib = base[((size_t)y1c * W_ + x0c) * C_ + c];
    const float Ic = base[((size_t)y0c * W_ + x1c) * C_ + c];
    const float Id = base[((size_t)y1c * W_ + x1c) * C_ + c];
    nxtw[(size_t)pix * C_ + c] = wa * Ia + wb * Ib + wc * Ic + wd * Id;
}

// ---------------------------------------------------------------------------
// 2) cost volume, redesigned.
// One block per (b,y): 576 threads = 9 waves; wave w owns dy = w-4 and its own
// LDS slab NL[w][c][xh] staged from row q=y+dy. prv chunk PL shared.
// Lane: cs = lane&3 (2 ch of 8-chunk), xg = lane>>2 (8 px). acc[8][9] in regs.
// All LDS accesses are 16B-aligned b128; register prefetch of next chunk
// overlaps global latency with compute.
// ---------------------------------------------------------------------------
__global__ __launch_bounds__(576, 3) void costvol_kernel(
    const float* __restrict__ prv, const float* __restrict__ nxtw,
    float* __restrict__ cost)
{
    constexpr int KC   = 8;     // channels per chunk
    constexpr int NSTR = 144;   // 140 halo'd row + pad, mult of 4 (16B align)
    constexpr int PSTR = 132;   // 128 + pad
    __shared__ float NL[9][KC][NSTR];   // 41472 B
    __shared__ float PL[KC][PSTR];      //  4224 B

    const int tid  = threadIdx.x;
    const int w    = tid >> 6;          // wave id 0..8
    const int lane = tid & 63;
    const int dy   = w - 4;
    const int r    = swz_row(blockIdx.x);   // b*H + y
    const int y    = r & 127;
    const int b    = r >> 7;
    const int q    = y + dy;
    const bool valid = (q >= 0) && (q < H_);

    // compute-phase lane tiling
    const int cs = lane & 3;
    const int xg = lane >> 2;
    const int x0 = xg * 8;

    // staging lane tiling (c-major: 4 scalar global loads -> one b128 LDS write)
    const int scl = lane & 7;           // channel within chunk
    const int sxq = lane >> 3;          // 0..7 -> xh quad
    const float* nrow = nxtw + ((size_t)(b * H_ + q) * W_) * C_;
    const int ppc = tid & 7;            // prow staging (tid < 256)
    const int ppq = tid >> 3;           // 0..31

    float acc[8][9];
    #pragma unroll
    for (int i = 0; i < 8; ++i)
        #pragma unroll
        for (int d = 0; d < 9; ++d) acc[i][d] = 0.0f;

    float nv[5][4];                     // prefetched nrow chunk
    float pv4[4];                       // prefetched prow chunk

    // prefetch chunk 0
    {
        const int c0 = 0;
        if (valid) {
            #pragma unroll
            for (int p = 0; p < 5; ++p) {
                const int xh0 = p * 32 + sxq * 4;
                if (xh0 < 140) {
                    #pragma unroll
                    for (int t = 0; t < 4; ++t) {
                        const int xs = xh0 + t - 4;
                        nv[p][t] = (xs >= 0 && xs < W_)
                                 ? nrow[(size_t)xs * C_ + c0 + scl] : 0.0f;
                    }
                }
            }
        }
        if (tid < 256) {
            #pragma unroll
            for (int t = 0; t < 4; ++t)
                pv4[t] = prv[((size_t)r * W_ + ppq * 4 + t) * C_ + c0 + ppc];
        }
    }

    for (int cc = 0; cc < 16; ++cc) {
        __syncthreads();                // previous chunk's LDS reads done
        if (valid) {
            #pragma unroll
            for (int p = 0; p < 5; ++p) {
                const int xh0 = p * 32 + sxq * 4;
                if (xh0 < 140)
                    *(float4*)&NL[w][scl][xh0] =
                        make_float4(nv[p][0], nv[p][1], nv[p][2], nv[p][3]);
            }
        }
        if (tid < 256)
            *(float4*)&PL[ppc][ppq * 4] =
                make_float4(pv4[0], pv4[1], pv4[2], pv4[3]);
        __syncthreads();

        // prefetch next chunk while computing this one
        if (cc < 15) {
            const int c0 = (cc + 1) * KC;
            if (valid) {
                #pragma unroll
                for (int p = 0; p < 5; ++p) {
                    const int xh0 = p * 32 + sxq * 4;
                    if (xh0 < 140) {
                        #pragma unroll
                        for (int t = 0; t < 4; ++t) {
                            const int xs = xh0 + t - 4;
                            nv[p][t] = (xs >= 0 && xs < W_)
                                     ? nrow[(size_t)xs * C_ + c0 + scl] : 0.0f;
                        }
                    }
                }
            }
            if (tid < 256) {
                #pragma unroll
                for (int t = 0; t < 4; ++t)
                    pv4[t] = prv[((size_t)r * W_ + ppq * 4 + t) * C_ + c0 + ppc];
            }
        }

        if (valid) {
            #pragma unroll
            for (int j = 0; j < 2; ++j) {
                const int c = cs + 4 * j;
                float pv[8];
                {
                    float4 p0 = *(const float4*)&PL[c][x0];
                    float4 p1 = *(const float4*)&PL[c][x0 + 4];
                    pv[0]=p0.x; pv[1]=p0.y; pv[2]=p0.z; pv[3]=p0.w;
                    pv[4]=p1.x; pv[5]=p1.y; pv[6]=p1.z; pv[7]=p1.w;
                }
                float n[16];
                {
                    float4 n0 = *(const float4*)&NL[w][c][x0];
                    float4 n1 = *(const float4*)&NL[w][c][x0 + 4];
                    float4 n2 = *(const float4*)&NL[w][c][x0 + 8];
                    float4 n3 = *(const float4*)&NL[w][c][x0 + 12];
                    n[0]=n0.x;  n[1]=n0.y;  n[2]=n0.z;  n[3]=n0.w;
                    n[4]=n1.x;  n[5]=n1.y;  n[6]=n1.z;  n[7]=n1.w;
                    n[8]=n2.x;  n[9]=n2.y;  n[10]=n2.z; n[11]=n2.w;
                    n[12]=n3.x; n[13]=n3.y; n[14]=n3.z; n[15]=n3.w;
                }
                #pragma unroll
                for (int i = 0; i < 8; ++i)
                    #pragma unroll
                    for (int d = 0; d < 9; ++d)
                        acc[i][d] += pv[i] * n[i + d];
            }
        }
    }

    // reduce over the 4 channel-splits (lane bits 0..1) and store
    #pragma unroll
    for (int i = 0; i < 8; ++i)
        #pragma unroll
        for (int d = 0; d < 9; ++d) {
            float v = acc[i][d];
            v += __shfl_xor(v, 1);
            v += __shfl_xor(v, 2);
            acc[i][d] = v;
        }
    if (cs == 0) {
        #pragma unroll
        for (int i = 0; i < 8; ++i) {
            const size_t base = ((size_t)r * W_ + (x0 + i)) * 81 + (size_t)(dy + 4) * 9;
            #pragma unroll
            for (int d = 0; d < 9; ++d)
                cost[base + d] = valid ? acc[i][d] * (1.0f / 128.0f) : 0.0f;
        }
    }
}

// ---------------------------------------------------------------------------
// 3) fused depthwise3x3 + pointwise + bias + mish, one block per (b,h) row.
// ---------------------------------------------------------------------------
template<int CIN, bool IS_L0>
__device__ __forceinline__ float read_x(const float* __restrict__ in,
    const float* __restrict__ cost, const float* __restrict__ prv,
    const float* __restrict__ flo, int b, int y, int x, int c)
{
    const size_t p = ((size_t)b * H_ + y) * W_ + x;
    if constexpr (IS_L0) {
        if (c < 81)  return cost[p * 81 + c];
        if (c < 209) return prv[p * 128 + (c - 81)];
        return flo[p * 2 + (c - 209)];
    } else {
        return in[p * CIN + c];
    }
}

template<int CIN, int COUT, int OPT, int PXT, bool ACT, bool IS_L0>
__global__ __launch_bounds__(256, 2) void sepconv_kernel(
    const float* __restrict__ in,
    const float* __restrict__ cost, const float* __restrict__ prv,
    const float* __restrict__ flo,
    const float* __restrict__ dw, const float* __restrict__ pw,
    const float* __restrict__ bias, float* __restrict__ out)
{
    constexpr int OGN  = COUT / OPT;          // 16 (L0-4) or 2 (L5) — pow2
    constexpr int DSTR = 132;                 // 128 + pad (mult of 4)
    static_assert(OGN * (W_ / PXT) == 256, "thread tiling must cover 256 threads");
    __shared__ float dwres[32 * DSTR];        // depthwise result, chunk of 32 ch
    __shared__ float pwl[32 * COUT];          // pw chunk [k][o]
    __shared__ float dwl[9 * CIN];            // depthwise weights [tap][c]

    const int tid = threadIdx.x;
    const int r   = swz_row(blockIdx.x);      // b*H + h
    const int h   = r & 127;
    const int b   = r >> 7;

    for (int i = tid; i < 9 * CIN; i += 256) dwl[i] = dw[i];

    const int og  = tid & (OGN - 1);
    const int pg  = tid / OGN;
    const int px0 = pg * PXT;

    float acc[PXT][OPT];
    #pragma unroll
    for (int i = 0; i < PXT; ++i)
        #pragma unroll
        for (int j = 0; j < OPT; ++j) acc[i][j] = 0.0f;

    for (int c0 = 0; c0 < CIN; c0 += 32) {
        const int kc = (CIN - c0 < 32) ? (CIN - c0) : 32;
        __syncthreads();                       // protect LDS reuse
        // stage pw chunk
        for (int idx = tid; idx < kc * COUT; idx += 256) {
            const int k = idx / COUT;
            const int o = idx - k * COUT;
            pwl[k * COUT + o] = pw[(size_t)(c0 + k) * COUT + o];
        }
        // depthwise for this channel chunk: entries (c in [0,32), pxg in [0,32))
        for (int e = tid; e < 32 * 32; e += 256) {
            const int c   = e & 31;
            const int pxg = e >> 5;
            if (c < kc) {
                const int cg = c0 + c;
                const int xb = pxg * 4;
                float wreg[9];
                #pragma unroll
                for (int t = 0; t < 9; ++t) wreg[t] = dwl[t * CIN + cg];
                float val[3][6];
                #pragma unroll
                for (int ky = 0; ky < 3; ++ky) {
                    const int yy = h + ky - 1;
                    const bool yok = (yy >= 0) & (yy < H_);
                    #pragma unroll
                    for (int m = 0; m < 6; ++m) {
                        const int xx = xb - 1 + m;
                        const bool ok = yok & (xx >= 0) & (xx < W_);
                        val[ky][m] = ok ? read_x<CIN, IS_L0>(in, cost, prv, flo, b, yy, xx, cg) : 0.0f;
                    }
                }
                float a[4];
                #pragma unroll
                for (int i = 0; i < 4; ++i) {
                    float s = 0.0f;
                    #pragma unroll
                    for (int ky = 0; ky < 3; ++ky)
                        #pragma unroll
                        for (int kx = 0; kx < 3; ++kx)
                            s += wreg[ky * 3 + kx] * val[ky][i + kx];
                    a[i] = s;
                }
                *(float4*)&dwres[c * DSTR + xb] = make_float4(a[0], a[1], a[2], a[3]);
            }
        }
        __syncthreads();
        // GEMM accumulate over this chunk
        #pragma unroll 4
        for (int k = 0; k < kc; ++k) {
            float av[PXT];
            if constexpr (PXT == 8) {
                float4 a0 = *(const float4*)&dwres[k * DSTR + px0];
                float4 a1 = *(const float4*)&dwres[k * DSTR + px0 + 4];
                av[0]=a0.x; av[1]=a0.y; av[2]=a0.z; av[3]=a0.w;
                av[4]=a1.x; av[5]=a1.y; av[6]=a1.z; av[7]=a1.w;
            } else {
                av[0] = dwres[k * DSTR + px0];
            }
            #pragma unroll
            for (int j = 0; j < OPT; ++j) {
                const float wv = pwl[k * COUT + og + OGN * j];
                #pragma unroll
                for (int i = 0; i < PXT; ++i)
                    acc[i][j] += av[i] * wv;
            }
        }
    }
    // epilogue: bias + mish + store
    float bj[OPT];
    #pragma unroll
    for (int j = 0; j < OPT; ++j) bj[j] = (bias != nullptr) ? bias[og + OGN * j] : 0.0f;
    #pragma unroll
    for (int i = 0; i < PXT; ++i) {
        const size_t obase = ((size_t)r * W_ + px0 + i) * COUT + og;
        #pragma unroll
        for (int j = 0; j < OPT; ++j) {
            const float x = acc[i][j] + bj[j];
            out[obase + (size_t)OGN * j] = ACT ? mish_f(x) : x;
        }
    }
}

// ---------------------------------------------------------------------------
extern "C" void kernel_launch(void* const* d_in, const int* in_sizes, int n_in,
                              void* d_out, int out_size, void* d_ws, size_t ws_size,
                              hipStream_t stream)
{
    (void)in_sizes; (void)n_in; (void)out_size; (void)ws_size;
    const float* prv = (const float*)d_in[0];
    const float* nxt = (const float*)d_in[1];
    const float* flo = (const float*)d_in[2];
    const float* dw0 = (const float*)d_in[3];
    const float* pw0 = (const float*)d_in[4];
    const float* b0  = (const float*)d_in[5];
    const float* dw1 = (const float*)d_in[6];
    const float* pw1 = (const float*)d_in[7];
    const float* b1  = (const float*)d_in[8];
    const float* dw2 = (const float*)d_in[9];
    const float* pw2 = (const float*)d_in[10];
    const float* b2  = (const float*)d_in[11];
    const float* dw3 = (const float*)d_in[12];
    const float* pw3 = (const float*)d_in[13];
    const float* b3  = (const float*)d_in[14];
    const float* dw4 = (const float*)d_in[15];
    const float* pw4 = (const float*)d_in[16];
    const float* b4  = (const float*)d_in[17];
    const float* dw5 = (const float*)d_in[18];
    const float* pw5 = (const float*)d_in[19];

    // ws layout: bufA [0, 64MiB) ; bufC [64MiB, 128MiB)  (cost aliases bufC)
    float* bufA  = (float*)d_ws;
    float* bufC  = (float*)((char*)d_ws + (size_t)67108864);
    float* costb = bufC;
    float* outp  = (float*)d_out;
    const float* nullf = nullptr;

    warp_kernel<<<65536, 256, 0, stream>>>(nxt, flo, bufA);
    costvol_kernel<<<1024, 576, 0, stream>>>(prv, bufA, costb);
    // L0: 211 -> 128 (reads cost/prv/flo virtually, nxtw in bufA is dead)
    sepconv_kernel<211, 128, 8, 8, true,  true ><<<1024, 256, 0, stream>>>(
        nullf, costb, prv, flo, dw0, pw0, b0, bufA);
    // L1: 128 -> 128
    sepconv_kernel<128, 128, 8, 8, true,  false><<<1024, 256, 0, stream>>>(
        bufA, nullf, nullf, nullf, dw1, pw1, b1, bufC);
    // L2: 128 -> 96
    sepconv_kernel<128,  96, 6, 8, true,  false><<<1024, 256, 0, stream>>>(
        bufC, nullf, nullf, nullf, dw2, pw2, b2, bufA);
    // L3: 96 -> 64
    sepconv_kernel< 96,  64, 4, 8, true,  false><<<1024, 256, 0, stream>>>(
        bufA, nullf, nullf, nullf, dw3, pw3, b3, bufC);
    // L4: 64 -> 32
    sepconv_kernel< 64,  32, 2, 8, true,  false><<<1024, 256, 0, stream>>>(
        bufC, nullf, nullf, nullf, dw4, pw4, b4, bufA);
    // L5: 32 -> 2, no bias, no activation
    sepconv_kernel< 32,   2, 1, 1, false, false><<<1024, 256, 0, stream>>>(
        bufA, nullf, nullf, nullf, dw5, pw5, nullf, outp);
}